// Round 6
// baseline (124.276 us; speedup 1.0000x reference)
//
#include <hip/hip_runtime.h>
#include <math.h>

#define BB 2
#define TT 512
#define UU 48
#define DD 512
#define HH 1024
#define KK 128

typedef _Float16 f16x8 __attribute__((ext_vector_type(8)));
typedef __fp16 fp16x2_t __attribute__((ext_vector_type(2)));
typedef float floatx4 __attribute__((ext_vector_type(4)));
typedef __attribute__((address_space(3))) _Float16 lds_f16;
typedef __attribute__((address_space(1))) const void g_cvoid;
typedef __attribute__((address_space(3))) void l_void;

// tanh from pre-scaled input z = 2*log2(e)*x (stored f16 by mid):
// tanh(x) = 1 - 2/(2^z + 1). 2 trans + ~5 VALU per 2 elems, +-inf safe.
__device__ __forceinline__ f16x8 tanh8z(f16x8 z) {
    f16x8 o;
#pragma unroll
    for (int i = 0; i < 8; i += 2) {
        float e0 = __builtin_amdgcn_exp2f((float)z[i]);
        float e1 = __builtin_amdgcn_exp2f((float)z[i + 1]);
        float r0 = __builtin_amdgcn_rcpf(e0 + 1.0f);
        float r1 = __builtin_amdgcn_rcpf(e1 + 1.0f);
        fp16x2_t p = __builtin_amdgcn_cvt_pkrtz(fmaf(-2.0f, r0, 1.0f),
                                                fmaf(-2.0f, r1, 1.0f));
        o[i] = (_Float16)p[0];
        o[i + 1] = (_Float16)p[1];
    }
    return o;
}

// ---------------- mid v5: unchanged ----------------------------------------
__global__ __launch_bounds__(256) void mid_kernel5(
    const float* __restrict__ img, const float* __restrict__ labf,
    const float* __restrict__ W1, const float* __restrict__ W2,
    const float* __restrict__ conv_w,
    const float* __restrict__ b1, const float* __restrict__ conv_b,
    const float* __restrict__ masks,
    _Float16* __restrict__ imgHf, _Float16* __restrict__ labHf,
    _Float16* __restrict__ W2s, float* __restrict__ seg_out) {
    int bid = blockIdx.x, tid = threadIdx.x;
    if (bid >= 624) {  // W2 swizzle: W2s[(h>>3)*1024 + k*8 + (h&7)] = W2[k][h]
        int base = (bid - 624) * 256 + tid;
#pragma unroll
        for (int i = 0; i < 32; ++i) {
            int o = base + i * 4096;
            int hg = o >> 10, kk2 = (o >> 3) & 127, hl = o & 7;
            W2s[o] = (_Float16)W2[(size_t)kk2 * HH + hg * 8 + hl];
        }
        return;
    }
    __shared__ __align__(16) _Float16 a_s[32][72];
    __shared__ __align__(16) _Float16 w_s[4096];  // [8 kgroups][64 n][8]
    const float* Arow;
    const float* Wbase;
    int r0, n0b, wstride, region;
    if (bid < 512) {
        region = 0; Arow = img; Wbase = W1 + 512; wstride = 2 * DD;
        int xcd = bid & 7, j = bid >> 3;
        r0 = (j & 31) * 32; n0b = (xcd * 2 + (j >> 5)) * 64;
    } else if (bid < 560) {
        region = 1; Arow = labf; Wbase = W1; wstride = 2 * DD;
        int i = bid - 512; r0 = (i % 3) * 32; n0b = (i / 3) * 64;
    } else {
        region = 2; Arow = img; Wbase = conv_w; wstride = DD;
        int i = bid - 560; r0 = (i >> 1) * 32; n0b = (i & 1) * 64;
    }
    int lane = tid & 63, wv = tid >> 6;
    int m0 = (wv & 1) * 16, n0w = (wv >> 1) * 32;
    int q = lane >> 4, r = lane & 15;
    int arow = tid >> 3, acol = (tid & 7) * 8;
    int wn = tid >> 2, wk0 = (tid & 3) * 16;  // 4 threads per W row, 16 k each
    const float* aptr = &Arow[(size_t)(r0 + arow) * DD + acol];
    const float* wptr = &Wbase[(size_t)(n0b + wn) * wstride + wk0];
    floatx4 acc[2] = {};
    float4 pa0, pa1, pw[4];
    pa0 = *(const float4*)aptr;
    pa1 = *(const float4*)(aptr + 4);
#pragma unroll
    for (int i2 = 0; i2 < 4; ++i2) pw[i2] = *(const float4*)(wptr + i2 * 4);
    for (int c = 0; c < 8; ++c) {
        f16x8 av;
        av[0] = (_Float16)pa0.x; av[1] = (_Float16)pa0.y;
        av[2] = (_Float16)pa0.z; av[3] = (_Float16)pa0.w;
        av[4] = (_Float16)pa1.x; av[5] = (_Float16)pa1.y;
        av[6] = (_Float16)pa1.z; av[7] = (_Float16)pa1.w;
        *(f16x8*)&a_s[arow][acol] = av;
        f16x8 w0, w1;
        w0[0] = (_Float16)pw[0].x; w0[1] = (_Float16)pw[0].y;
        w0[2] = (_Float16)pw[0].z; w0[3] = (_Float16)pw[0].w;
        w0[4] = (_Float16)pw[1].x; w0[5] = (_Float16)pw[1].y;
        w0[6] = (_Float16)pw[1].z; w0[7] = (_Float16)pw[1].w;
        w1[0] = (_Float16)pw[2].x; w1[1] = (_Float16)pw[2].y;
        w1[2] = (_Float16)pw[2].z; w1[3] = (_Float16)pw[2].w;
        w1[4] = (_Float16)pw[3].x; w1[5] = (_Float16)pw[3].y;
        w1[6] = (_Float16)pw[3].z; w1[7] = (_Float16)pw[3].w;
        int kg = wk0 >> 3;
        *(f16x8*)&w_s[((kg + 0) * 64 + wn) * 8] = w0;
        *(f16x8*)&w_s[((kg + 1) * 64 + wn) * 8] = w1;
        __syncthreads();
        if (c < 7) {
            int cb = (c + 1) * 64;
            pa0 = *(const float4*)(aptr + cb);
            pa1 = *(const float4*)(aptr + cb + 4);
#pragma unroll
            for (int i2 = 0; i2 < 4; ++i2)
                pw[i2] = *(const float4*)(wptr + cb + i2 * 4);
        }
#pragma unroll
        for (int kt = 0; kt < 2; ++kt) {
            f16x8 af = *(const f16x8*)&a_s[m0 + r][kt * 32 + q * 8];
#pragma unroll
            for (int nt = 0; nt < 2; ++nt) {
                f16x8 bf = *(const f16x8*)
                    &w_s[((kt * 4 + q) * 64 + n0w + nt * 16 + r) * 8];
                acc[nt] = __builtin_amdgcn_mfma_f32_16x16x32_f16(
                    af, bf, acc[nt], 0, 0, 0);
            }
        }
        __syncthreads();
    }
    const float SC = 2.8853900817779268f;  // 2*log2(e): pre-scale for tanh8z
    if (region == 0) {
#pragma unroll
        for (int nt = 0; nt < 2; ++nt) {
            int n = n0b + n0w + nt * 16 + r;
#pragma unroll
            for (int rr = 0; rr < 4; ++rr)
                imgHf[(size_t)(r0 + m0 + 4 * q + rr) * HH + n] =
                    (_Float16)(acc[nt][rr] * SC);
        }
    } else if (region == 1) {
#pragma unroll
        for (int nt = 0; nt < 2; ++nt) {
            int n = n0b + n0w + nt * 16 + r;
            float bv = b1[n];
#pragma unroll
            for (int rr = 0; rr < 4; ++rr)
                labHf[(size_t)(r0 + m0 + 4 * q + rr) * HH + n] =
                    (_Float16)((acc[nt][rr] + bv) * SC);
        }
    } else {
#pragma unroll
        for (int nt = 0; nt < 2; ++nt) {
            int k = n0b + n0w + nt * 16 + r;
            float bv = conv_b[k];
#pragma unroll
            for (int rr = 0; rr < 4; ++rr) {
                int row = r0 + m0 + 4 * q + rr;
                int b = row >> 9, t = row & 511;
                seg_out[((size_t)b * KK + k) * TT + t] =
                    (acc[nt][rr] + bv) * masks[row];
            }
        }
    }
}

// ---------------- joint v11: full-DMA 2-phase pipeline ---------------------
// 512 blocks x 192 thr (3 waves x 32 rows = 96 rows), 56.5 KB LDS ->
// 2 independent blocks/CU. ALL operands (A-img, W2, lab) arrive by
// global_load_lds DMA (0 VGPRs, un-sinkable), double-buffered. Per chunk:
// issue c+1's ~10 DMAs, compute c (tanh+MFMA hides latency), vmcnt(0)+
// s_barrier. A DMA lane-mapping makes LDS layout [colchunk][row] ->
// fragment reads are 64 distinct 16B slots: zero bank conflicts, no swizzle.
__global__ __launch_bounds__(192) void joint_kernel11(
    const _Float16* __restrict__ imgHf,  // [B*T][H], pre-scaled 2log2e
    const _Float16* __restrict__ labHf,  // [B*U][H], (.+b1) pre-scaled
    const _Float16* __restrict__ W2s,    // swizzled [(h>>3)][k][h&7]
    const float* __restrict__ b2,
    float* __restrict__ out) {           // [B*U*T][K]
    __shared__ __align__(16) _Float16 A_s[2][6144];  // 2 x 12 KB img tiles
    __shared__ __align__(16) _Float16 W_s[2][8192];  // 2 x 16 KB W2 chunk
    __shared__ __align__(16) _Float16 L_s[2][128];   // 2 x 256 B lab rows
    int tid = threadIdx.x, bid = blockIdx.x;
    int lane = tid & 63, wv = tid >> 6;  // 3 waves x 32 rows
    int ql = lane >> 4, r = lane & 15;
    int g0 = bid * 96 + wv * 32;         // wave's first flat (b,u,t) row
    int buA = (bid * 96) >> 9, buB = (bid * 96 + 95) >> 9;  // block's lab rows
    int bu0 = (g0 + r) >> 9, bu1 = (g0 + 16 + r) >> 9;
    int sel0 = (bu0 == buA) ? 0 : 64;    // lane's lab row within L_s
    int sel1 = (bu1 == buA) ? 0 : 64;
    floatx4 acc0[8] = {}, acc1[8] = {};

    // DMA stage of one 64-h chunk into buffer `buf` (cb = chunk*64)
    auto stage = [&](int cb, int buf) {
        int cc = lane >> 4;  // col-chunk 0..3
        // A-img: 4 instrs/wave, each stages 16 rows x 64 B. Lane (r,cc):
        // src row g0+m*16+r, cols cb+h*32+cc*8; dest linear lane*16 ->
        // LDS layout [wv][m*2+h][cc*256B][r*16B]  (read: ql*256+r*16, 64
        // distinct 16B slots -> conflict-free)
#pragma unroll
        for (int mh = 0; mh < 4; ++mh) {
            int fl = g0 + (mh >> 1) * 16 + r;
            int irow = ((fl >= UU * TT) ? TT : 0) + (fl & 511);
            const _Float16* src =
                imgHf + (size_t)irow * HH + cb + (mh & 1) * 32 + cc * 8;
            lds_f16* dst = (lds_f16*)&A_s[buf][(wv * 4 + mh) * 512 + lane * 8];
            __builtin_amdgcn_global_load_lds((g_cvoid*)src, (l_void*)dst,
                                             16, 0, 0);
        }
        // W2 chunk (16 KB = 16 instrs): waves 0,1: 5 each; wave 2: 6
        int i0 = wv * 5, nW = (wv == 2) ? 6 : 5;
#pragma unroll
        for (int j = 0; j < 6; ++j) {
            if (j < nW) {
                const _Float16* src =
                    W2s + (size_t)cb * 128 + (i0 + j) * 512 + lane * 8;
                lds_f16* dst =
                    (lds_f16*)&W_s[buf][(i0 + j) * 512 + lane * 8];
                __builtin_amdgcn_global_load_lds((g_cvoid*)src, (l_void*)dst,
                                                 16, 0, 0);
            }
        }
        // lab rows (256 B): wave 0, lanes 0-15
        if (wv == 0 && lane < 16) {
            int bu = (lane < 8) ? buA : buB;
            const _Float16* src = labHf + (size_t)bu * HH + cb + (lane & 7) * 8;
            lds_f16* dst = (lds_f16*)&L_s[buf][lane * 8];
            __builtin_amdgcn_global_load_lds((g_cvoid*)src, (l_void*)dst,
                                             16, 0, 0);
        }
    };

    // prologue: chunk 0 -> buf 0
    stage(0, 0);
    asm volatile("s_waitcnt vmcnt(0)" ::: "memory");
    __builtin_amdgcn_s_barrier();
    asm volatile("" ::: "memory");

#pragma unroll 2
    for (int c = 0; c < 16; ++c) {
        int cur = c & 1;
        if (c < 15) stage((c + 1) * 64, cur ^ 1);  // fire-and-forget DMA
        // ---- compute chunk c from buf cur ----
        const _Float16* Ab = &A_s[cur][wv * 2048];
        const _Float16* Wb = W_s[cur];
        const _Float16* Lb = L_s[cur];
        f16x8 i0A = *(const f16x8*)&Ab[0 * 512 + ql * 128 + r * 8];
        f16x8 i0B = *(const f16x8*)&Ab[1 * 512 + ql * 128 + r * 8];
        f16x8 i1A = *(const f16x8*)&Ab[2 * 512 + ql * 128 + r * 8];
        f16x8 i1B = *(const f16x8*)&Ab[3 * 512 + ql * 128 + r * 8];
        f16x8 l0A = *(const f16x8*)&Lb[sel0 + ql * 8];
        f16x8 l0B = *(const f16x8*)&Lb[sel0 + 32 + ql * 8];
        f16x8 l1A = *(const f16x8*)&Lb[sel1 + ql * 8];
        f16x8 l1B = *(const f16x8*)&Lb[sel1 + 32 + ql * 8];
        f16x8 a0A = tanh8z(i0A + l0A);
        f16x8 a1A = tanh8z(i1A + l1A);
#pragma unroll
        for (int nt = 0; nt < 8; ++nt) {  // each bf feeds BOTH m-tiles
            f16x8 bf = *(const f16x8*)&Wb[(ql * 128 + nt * 16 + r) * 8];
            acc0[nt] = __builtin_amdgcn_mfma_f32_16x16x32_f16(
                a0A, bf, acc0[nt], 0, 0, 0);
            acc1[nt] = __builtin_amdgcn_mfma_f32_16x16x32_f16(
                a1A, bf, acc1[nt], 0, 0, 0);
        }
        f16x8 a0B = tanh8z(i0B + l0B);
        f16x8 a1B = tanh8z(i1B + l1B);
#pragma unroll
        for (int nt = 0; nt < 8; ++nt) {
            f16x8 bf = *(const f16x8*)&Wb[((4 + ql) * 128 + nt * 16 + r) * 8];
            acc0[nt] = __builtin_amdgcn_mfma_f32_16x16x32_f16(
                a0B, bf, acc0[nt], 0, 0, 0);
            acc1[nt] = __builtin_amdgcn_mfma_f32_16x16x32_f16(
                a1B, bf, acc1[nt], 0, 0, 0);
        }
        if (c < 15) {
            // drain own DMAs (issued one full chunk ago -> near-free) and
            // sync so buf cur^1 is readable / buf cur is rewritable
            asm volatile("s_waitcnt vmcnt(0)" ::: "memory");
            __builtin_amdgcn_s_barrier();
            asm volatile("" ::: "memory");
        }
    }
    // epilogue: +b2, in-register log-softmax per 16-lane group's 128 cols
    float b2v[8];
#pragma unroll
    for (int nt = 0; nt < 8; ++nt) b2v[nt] = b2[nt * 16 + r];
#pragma unroll
    for (int mt = 0; mt < 2; ++mt) {
        float* obase = out + (size_t)(g0 + mt * 16 + 4 * ql) * KK;
#pragma unroll
        for (int rr = 0; rr < 4; ++rr) {
            float v[8];
            float mx = -INFINITY;
#pragma unroll
            for (int nt = 0; nt < 8; ++nt) {
                v[nt] = (mt ? acc1[nt][rr] : acc0[nt][rr]) + b2v[nt];
                mx = fmaxf(mx, v[nt]);
            }
            mx = fmaxf(mx, __shfl_xor(mx, 1, 16));
            mx = fmaxf(mx, __shfl_xor(mx, 2, 16));
            mx = fmaxf(mx, __shfl_xor(mx, 4, 16));
            mx = fmaxf(mx, __shfl_xor(mx, 8, 16));
            float s = 0.f;
#pragma unroll
            for (int nt = 0; nt < 8; ++nt) s += __expf(v[nt] - mx);
            s += __shfl_xor(s, 1, 16);
            s += __shfl_xor(s, 2, 16);
            s += __shfl_xor(s, 4, 16);
            s += __shfl_xor(s, 8, 16);
            float lse = mx + __logf(s);
#pragma unroll
            for (int nt = 0; nt < 8; ++nt)
                obase[(size_t)rr * KK + nt * 16 + r] = v[nt] - lse;
        }
    }
}

extern "C" void kernel_launch(void* const* d_in, const int* in_sizes, int n_in,
                              void* d_out, int out_size, void* d_ws, size_t ws_size,
                              hipStream_t stream) {
    const float* img    = (const float*)d_in[0];
    const float* labf   = (const float*)d_in[1];
    const float* masks  = (const float*)d_in[2];
    const float* W1     = (const float*)d_in[3];
    const float* b1     = (const float*)d_in[4];
    const float* W2     = (const float*)d_in[5];
    const float* b2     = (const float*)d_in[6];
    const float* conv_w = (const float*)d_in[7];
    const float* conv_b = (const float*)d_in[8];
    float* out = (float*)d_out;

    _Float16* base  = (_Float16*)d_ws;
    _Float16* imgHf = base;                    // [1024][1024]
    _Float16* labHf = imgHf + 1024 * 1024;     // [96][1024]
    _Float16* W2s   = labHf + 96 * 1024;       // [H/8][K][8] = 131072

    mid_kernel5<<<640, 256, 0, stream>>>(img, labf, W1, W2, conv_w,
                                         b1, conv_b, masks,
                                         imgHf, labHf, W2s, out);
    joint_kernel11<<<512, 192, 0, stream>>>(imgHf, labHf, W2s, b2,
                                            out + (size_t)BB * KK * TT);
}